// Round 9
// baseline (20.422 us; speedup 1.0000x reference)
//
#include <hip/hip_runtime.h>

#define SCALE 28.853900817779268f   // 20*log2(e)
#define L2E   1.4426950408889634f   // log2(e)
#define M 2048                      // histogram bins over p in [0,1]
#define T 1024                      // threads per block
#define CPC 16                      // blocks per class (R9: 32->16, halves L2 feed)
#define QB (M/CPC)                  // 128 mk-bins per block (STRIDED: mk = ch + CPC*q)

__device__ __forceinline__ float fexp2(float x){ return __builtin_amdgcn_exp2f(x); }
__device__ __forceinline__ float frcp (float x){ return __builtin_amdgcn_rcpf(x); }

#define WRED64(x) { _Pragma("unroll") for (int _o = 32; _o; _o >>= 1) x += __shfl_down(x, _o, 64); }
#define ALOAD(p) __hip_atomic_load((p), __ATOMIC_RELAXED, __HIP_MEMORY_SCOPE_AGENT)

// 128 blocks = 8 classes x 16 chunks. R8 established: kernel ~= 4us, dominated
// by phase 1's redundant L2 feed (32 blocks/XCD x 288KB = 9.2MB/XCD ~ 2.1us);
// phase 2 (g-table + uniform skip) is ~0.3us. So CPC 32->16 halves the L2 term
// (-1.0us) and only doubles cheap table iterations (+0.35us). CPC=8 is worse
// (table iters grow faster than L2 shrinks). Everything else is the proven R8
// structure: single LDS int histogram (bit-deterministic), g-table phase 2
// (pair term depends only on bin difference d=mk-mj; +0.5 offsets cancel),
// overwrite-only workspace (atomicExch) + persistent mod-NB finalize ticket.
__global__ __launch_bounds__(1024)
void k_fused(const float* __restrict__ logits, const int* __restrict__ tgt,
             float* __restrict__ out, unsigned* __restrict__ ticket,
             float* __restrict__ gpart, int* __restrict__ ccnt, int N){
  const int b = blockIdx.x, NB = (int)gridDim.x;
  const int c = b >> 4, ch = b & (CPC-1);
  const int tid = threadIdx.x, lane = tid & 63, w = tid >> 6;
  const float invM = 1.0f / (float)M;

  __shared__ int   HP[M];            // packed hist: low16 all rows, high16 pos
  __shared__ float g[2*M];           // g[d+2047], d = mk-mj in (-M, M)
  __shared__ int   wnp[16];
  __shared__ float rw[16];
  __shared__ float scs[8];
  __shared__ int   lastflag;

  // setup: zero histogram, build difference-sigmoid table (4 trans/thread)
  ((int2*)HP)[tid] = make_int2(0, 0);
  #pragma unroll
  for (int r = 0; r < 4; ++r){
    int idx = tid + 1024*r;
    if (idx < 2*M-1){
      float d = (float)(idx - (M-1));
      g[idx] = frcp(1.0f + fexp2(SCALE * d * invM));  // == frcp(fmaf(Bk,Ej,1))
    }
  }
  __syncthreads();

  // ---- phase 1: class-c histogram over ALL rows (L2-fed, redundant x16) ----
  const float4* l4 = (const float4*)logits;
  #pragma unroll 4
  for (int i = tid; i < N; i += T){
    float4 A = l4[2*i], B4 = l4[2*i+1];
    float e0=fexp2(A.x *L2E), e1=fexp2(A.y *L2E), e2=fexp2(A.z *L2E), e3=fexp2(A.w *L2E);
    float e4=fexp2(B4.x*L2E), e5=fexp2(B4.y*L2E), e6=fexp2(B4.z*L2E), e7=fexp2(B4.w*L2E);
    float s = ((e0+e1)+(e2+e3))+((e4+e5)+(e6+e7));
    float ec = e0;                   // static select of class-c exponential
    ec=(c==1)?e1:ec; ec=(c==2)?e2:ec; ec=(c==3)?e3:ec;
    ec=(c==4)?e4:ec; ec=(c==5)?e5:ec; ec=(c==6)?e6:ec; ec=(c==7)?e7:ec;
    float p = ec * frcp(s);
    int bin = min((int)(p * (float)M), M-1);
    int inc = 1 + ((tgt[i] == c) ? (1 << 16) : 0);
    atomicAdd(&HP[bin], inc);        // LDS, integer -> deterministic
  }
  __syncthreads();

  // ---- fragment extraction: per thread 2 Hneg values + np partial ----
  float Hj0, Hj1; int np_part;
  {
    const int hp0 = HP[tid], hp1 = HP[tid + T];
    const int p0 = hp0 >> 16, p1 = hp1 >> 16;
    np_part = p0 + p1;
    Hj0 = (float)((hp0 & 0xFFFF) - p0);
    Hj1 = (float)((hp1 & 0xFFFF) - p1);
  }
  WRED64(np_part)
  if (lane == 0) wnp[w] = np_part;

  // ---- phase 2: pair partial over 128 STRIDED mk-bins via g-table ----
  float tot = 0.f;
  const int i0 = ch + (M-1) - tid;   // g-index for q=0, mj0=tid
  #pragma unroll 4
  for (int q = 0; q < QB; ++q){
    int Pki = HP[ch + CPC*q] >> 16;  // LDS uniform broadcast
    if (Pki == 0) continue;          // wave-uniform skip
    float g0 = g[i0 + CPC*q];        // mj0=tid (consecutive lanes, no conflict)
    float g1 = g[i0 + CPC*q - 1024]; // mj1=tid+1024
    tot += (float)Pki * fmaf(Hj0, g0, Hj1 * g1);
  }
  WRED64(tot)
  if (lane == 0) rw[w] = tot;
  __syncthreads();                   // rw + wnp visible
  if (tid == 0){
    float bt = 0.f;
    #pragma unroll
    for (int i = 0; i < 16; ++i) bt += rw[i];
    atomicExch(&gpart[b], bt);       // overwrite -> poison/stale-safe
    if (ch == 0){                    // one writer/class; np identical in all
      int snp = 0;
      #pragma unroll
      for (int i = 0; i < 16; ++i) snp += wnp[i];
      atomicExch(&ccnt[c], snp);
    }
    __threadfence();                 // release
    unsigned old = atomicAdd(ticket, 1u);  // persistent mod-NB ticket
    lastflag = ((old % (unsigned)NB) == (unsigned)(NB - 1));
  }
  __syncthreads();
  if (!lastflag) return;

  // ---- finalize (last block; fixed order -> deterministic) ----
  if (tid == 0) __threadfence();     // acquire
  __syncthreads();
  if (tid < 128){                    // 8 classes x 16 chunks
    int c2 = tid >> 4, l = tid & 15;
    float s = ALOAD(&gpart[c2*CPC + l]);   // agent-scope load (no RMW)
    #pragma unroll
    for (int o = 8; o; o >>= 1) s += __shfl_down(s, o, 16);
    if (l == 0) scs[c2] = s;
  }
  __syncthreads();
  if (tid < 8){
    int np = ALOAD(&ccnt[tid]);
    int nn = N - np;
    bool valid = (np > 0 && nn > 0);
    float t = valid ? scs[tid] / ((float)np * (float)nn) : 0.f;
    float f = valid ? 1.f : 0.f;
    #pragma unroll
    for (int o = 4; o; o >>= 1){
      t += __shfl_down(t, o, 8);
      f += __shfl_down(f, o, 8);
    }
    if (tid == 0) out[0] = (f > 0.f) ? (1.0f - t / f) : 0.0f;
  }
}

extern "C" void kernel_launch(void* const* d_in, const int* in_sizes, int n_in,
                              void* d_out, int out_size, void* d_ws, size_t ws_size,
                              hipStream_t stream) {
    const float* logits = (const float*)d_in[0];
    const int*   tgt    = (const int*)d_in[1];
    float* out = (float*)d_out;
    int N = in_sizes[1];

    unsigned* ticket = (unsigned*)d_ws;                // [0] persistent mod-NB
    float* gpart = (float*)d_ws + 32;                  // [32..159] block partials
    int*   ccnt  = (int*)((float*)d_ws + 288);         // [288..295]

    k_fused<<<8*CPC, T, 0, stream>>>(logits, tgt, out, ticket, gpart, ccnt, N);
}

// Round 10
// 17.200 us; speedup vs baseline: 1.1873x; 1.1873x over previous
//
#include <hip/hip_runtime.h>

#define SCALE 28.853900817779268f   // 20*log2(e)
#define L2E   1.4426950408889634f   // log2(e)
#define M 2048                      // histogram bins over p in [0,1]
#define T 1024                      // threads per block
#define CPC 32                      // blocks per class (R9's 16 regressed; revert)
#define QB (M/CPC)                  // 64 mk-bins per block (STRIDED: mk = ch + CPC*q)

__device__ __forceinline__ float fexp2(float x){ return __builtin_amdgcn_exp2f(x); }
__device__ __forceinline__ float frcp (float x){ return __builtin_amdgcn_rcpf(x); }
__device__ __forceinline__ float Gfun(int x, float invM){   // g(d)=1/(1+2^(S*d/M)), x=d+2047
  return frcp(1.0f + fexp2(SCALE * (float)(x - (M-1)) * invM));
}

#define WRED64(x) { _Pragma("unroll") for (int _o = 32; _o; _o >>= 1) x += __shfl_down(x, _o, 64); }
#define ALOAD(p) __hip_atomic_load((p), __ATOMIC_RELAXED, __HIP_MEMORY_SCOPE_AGENT)

// 256 blocks = 8 classes x 32 chunks (R8 grid/skeleton). R9 taught us phase 2
// was ~64cy/iter: LDS-pipe-bound (16 waves x ~115 LDS instrs) + a dependent
// uniform-load->branch chain. This round minimizes LDS instructions:
//  * mj pair = (2t, 2t+1): both g-values in ONE ds_read_b64 from a float2
//    table G2[2048] with the block's ch-parity baked in (exact alignment).
//  * Pk register-gather: compact staging Pkc[64] -> one conflict-free
//    lane-indexed b32 per wave, per-q broadcast via v_readlane (VALU pipe).
//  * NO zero-skip branch: Pk=0 terms add exactly +0.0f (operands finite) ->
//    bit-identical, and the 120cy dependent branch chain disappears.
//  -> 65 LDS instrs/wave (was ~115), 4 independent accumulators.
// Phase 1, extraction, overwrite-only workspace (atomicExch) + mod-NB
// finalize ticket are R8-exact. Integer histogram -> bit-deterministic.
__global__ __launch_bounds__(1024)
void k_fused(const float* __restrict__ logits, const int* __restrict__ tgt,
             float* __restrict__ out, unsigned* __restrict__ ticket,
             float* __restrict__ gpart, int* __restrict__ ccnt, int N){
  const int b = blockIdx.x, NB = (int)gridDim.x;
  const int c = b >> 5, ch = b & (CPC-1);
  const int tid = threadIdx.x, lane = tid & 63, w = tid >> 6;
  const float invM = 1.0f / (float)M;
  const int s = ch & 1;              // table parity for this block

  __shared__ int    HP[M];           // packed hist: low16 all rows, high16 pos
  __shared__ float2 G2[M];           // G2[e] = {G(2e+s), G(2e+s+1)}
  __shared__ int    Pkc[64];         // compact Pk staging (this block's mk set)
  __shared__ int    wnp[16];
  __shared__ float  rw[16];
  __shared__ float  scs[8];
  __shared__ int    lastflag;

  // setup: zero histogram, build paired difference-sigmoid table (4 trans/thr)
  ((int2*)HP)[tid] = make_int2(0, 0);
  G2[tid]        = make_float2(Gfun(2*tid + s,          invM),
                               Gfun(2*tid + s + 1,      invM));
  G2[tid + 1024] = make_float2(Gfun(2*(tid+1024) + s,   invM),
                               Gfun(2*(tid+1024) + s+1, invM));
  __syncthreads();

  // ---- phase 1: class-c histogram over ALL rows (R8-exact) ----
  const float4* l4 = (const float4*)logits;
  #pragma unroll 2
  for (int i = tid; i < N; i += T){
    float4 A = l4[2*i], B4 = l4[2*i+1];
    float e0=fexp2(A.x *L2E), e1=fexp2(A.y *L2E), e2=fexp2(A.z *L2E), e3=fexp2(A.w *L2E);
    float e4=fexp2(B4.x*L2E), e5=fexp2(B4.y*L2E), e6=fexp2(B4.z*L2E), e7=fexp2(B4.w*L2E);
    float sm = ((e0+e1)+(e2+e3))+((e4+e5)+(e6+e7));
    float ec = e0;                   // static select of class-c exponential
    ec=(c==1)?e1:ec; ec=(c==2)?e2:ec; ec=(c==3)?e3:ec;
    ec=(c==4)?e4:ec; ec=(c==5)?e5:ec; ec=(c==6)?e6:ec; ec=(c==7)?e7:ec;
    float p = ec * frcp(sm);
    int bin = min((int)(p * (float)M), M-1);
    int inc = 1 + ((tgt[i] == c) ? (1 << 16) : 0);
    atomicAdd(&HP[bin], inc);        // LDS, integer -> deterministic
  }
  __syncthreads();

  // ---- extraction: thread t owns bins (2t, 2t+1); stage compact Pk ----
  float Hj0, Hj1; int np_part;
  {
    int2 hp = ((const int2*)HP)[tid];
    int p0 = hp.x >> 16, p1 = hp.y >> 16;
    np_part = p0 + p1;
    Hj0 = (float)((hp.x & 0xFFFF) - p0);
    Hj1 = (float)((hp.y & 0xFFFF) - p1);
  }
  if (tid < 64) Pkc[tid] = HP[ch + CPC*tid];   // this block's 64 mk bins
  WRED64(np_part)
  if (lane == 0) wnp[w] = np_part;
  __syncthreads();                   // Pkc ready (wnp also covered)

  // ---- phase 2: 64 STRIDED mk-bins; 1 gather + 64 b64 reads per wave ----
  // term (q, mj): d = ch+32q-mj; mj0=2t -> x0 = d0+2047; mj1=2t+1 -> x1 = x0-1
  // {x1,x0} = {2j+s, 2j+s+1},  j = (2046+ch-s)/2 + 16q - t
  const int jb = ((2046 + ch - s) >> 1) - tid;
  const int pkv = Pkc[lane];         // lane q holds Pk(q); conflict-free b32
  float t0 = 0.f, t1 = 0.f, t2 = 0.f, t3 = 0.f;
  #pragma unroll
  for (int q = 0; q < QB; q += 4){
    #pragma unroll
    for (int u = 0; u < 4; ++u){
      int pq = __builtin_amdgcn_readlane(pkv, q + u);   // VALU broadcast
      float Pk = (float)(pq >> 16);
      float2 gg = G2[jb + 16*(q + u)];                  // one ds_read_b64
      float term = fmaf(Hj0, gg.y, Hj1 * gg.x);         // gg.y=g(mj0), gg.x=g(mj1)
      if (u == 0) t0 = fmaf(Pk, term, t0);
      if (u == 1) t1 = fmaf(Pk, term, t1);
      if (u == 2) t2 = fmaf(Pk, term, t2);
      if (u == 3) t3 = fmaf(Pk, term, t3);
    }
  }
  float tot = (t0 + t1) + (t2 + t3);
  WRED64(tot)
  if (lane == 0) rw[w] = tot;
  __syncthreads();                   // rw visible
  if (tid == 0){
    float bt = 0.f;
    #pragma unroll
    for (int i = 0; i < 16; ++i) bt += rw[i];
    atomicExch(&gpart[b], bt);       // overwrite -> poison/stale-safe
    if (ch == 0){                    // one writer/class; np identical in all
      int snp = 0;
      #pragma unroll
      for (int i = 0; i < 16; ++i) snp += wnp[i];
      atomicExch(&ccnt[c], snp);
    }
    __threadfence();                 // release
    unsigned old = atomicAdd(ticket, 1u);  // persistent mod-NB ticket
    lastflag = ((old % (unsigned)NB) == (unsigned)(NB - 1));
  }
  __syncthreads();
  if (!lastflag) return;

  // ---- finalize (last block; fixed order -> deterministic) ----
  if (tid == 0) __threadfence();     // acquire
  __syncthreads();
  if (tid < 256){
    int c2 = tid >> 5, l = tid & 31;
    float sp = ALOAD(&gpart[c2*CPC + l]);  // agent-scope load (no RMW)
    #pragma unroll
    for (int o = 16; o; o >>= 1) sp += __shfl_down(sp, o, 32);
    if (l == 0) scs[c2] = sp;
  }
  __syncthreads();
  if (tid < 8){
    int np = ALOAD(&ccnt[tid]);
    int nn = N - np;
    bool valid = (np > 0 && nn > 0);
    float t = valid ? scs[tid] / ((float)np * (float)nn) : 0.f;
    float f = valid ? 1.f : 0.f;
    #pragma unroll
    for (int o = 4; o; o >>= 1){
      t += __shfl_down(t, o, 8);
      f += __shfl_down(f, o, 8);
    }
    if (tid == 0) out[0] = (f > 0.f) ? (1.0f - t / f) : 0.0f;
  }
}

extern "C" void kernel_launch(void* const* d_in, const int* in_sizes, int n_in,
                              void* d_out, int out_size, void* d_ws, size_t ws_size,
                              hipStream_t stream) {
    const float* logits = (const float*)d_in[0];
    const int*   tgt    = (const int*)d_in[1];
    float* out = (float*)d_out;
    int N = in_sizes[1];

    unsigned* ticket = (unsigned*)d_ws;                // [0] persistent mod-NB
    float* gpart = (float*)d_ws + 32;                  // [32..287] block partials
    int*   ccnt  = (int*)((float*)d_ws + 288);         // [288..295]

    k_fused<<<8*CPC, T, 0, stream>>>(logits, tgt, out, ticket, gpart, ccnt, N);
}